// Round 4
// baseline (270.285 us; speedup 1.0000x reference)
//
#include <hip/hip_runtime.h>
#include <hip/hip_bf16.h>

#define D 128
#define EDGE_DIM 6
#define LN_EPS 1e-5f

static __device__ __forceinline__ float bf_lo(unsigned u) { return __uint_as_float(u << 16); }
static __device__ __forceinline__ float bf_hi(unsigned u) { return __uint_as_float(u & 0xffff0000u); }
static __device__ __forceinline__ unsigned short f2bf(float f) {
    __hip_bfloat16 h = __float2bfloat16(f);
    return *reinterpret_cast<unsigned short*>(&h);
}

// ---------- kernel 1: Wc = We @ Wm2, bc = be @ Wm2 + bm (8 waves) ----------
__global__ __launch_bounds__(1024)
void prep_wc(const float* __restrict__ We, const float* __restrict__ be,
             const float* __restrict__ Wm, const float* __restrict__ bm,
             float* __restrict__ Wc, float* __restrict__ bc) {
    const int d = threadIdx.x & (D - 1);
    const int grp = threadIdx.x >> 7;  // 0..7
    __shared__ float sred[7][8][D];
    float acc[EDGE_DIM] = {0.f, 0.f, 0.f, 0.f, 0.f, 0.f};
    float accb = 0.f;
    for (int j = grp * 16; j < grp * 16 + 16; ++j) {
        float wm2 = Wm[(D + j) * D + d];
        accb = fmaf(be[j], wm2, accb);
#pragma unroll
        for (int k = 0; k < EDGE_DIM; ++k)
            acc[k] = fmaf(We[k * D + j], wm2, acc[k]);
    }
#pragma unroll
    for (int k = 0; k < EDGE_DIM; ++k) sred[k][grp][d] = acc[k];
    sred[6][grp][d] = accb;
    __syncthreads();
    if (threadIdx.x < D) {
#pragma unroll
        for (int k = 0; k < EDGE_DIM; ++k) {
            float s = 0.f;
#pragma unroll
            for (int g = 0; g < 8; ++g) s += sred[k][g][d];
            Wc[k * D + d] = s;
        }
        float s = 0.f;
#pragma unroll
        for (int g = 0; g < 8; ++g) s += sred[6][g][d];
        bc[d] = s + bm[d];
    }
}

// ---------- kernel 2: out_bf16[n][d] = bias[d] + sum_k A[n][k] * W[k][d] ----------
template <bool A_BF16>
__global__ __launch_bounds__(128)
void gemm128(const void* __restrict__ Ain, const float* __restrict__ W,
             const float* __restrict__ bias, unsigned short* __restrict__ out, int nrows) {
    const int d = threadIdx.x;
    float w[D];
#pragma unroll
    for (int k = 0; k < D; ++k) w[k] = W[k * D + d];
    const float b = bias ? bias[d] : 0.0f;

    __shared__ float4 sX[8 * 32];
    const int ntiles = (nrows + 7) / 8;

    for (int tile = blockIdx.x; tile < ntiles; tile += gridDim.x) {
        if (A_BF16) {
            const uint4* A16 = (const uint4*)Ain;  // 8 bf16 per uint4
            const int rowin = d >> 4;
            uint4 u = (tile * 8 + rowin < nrows) ? A16[(size_t)tile * 128 + d]
                                                 : make_uint4(0, 0, 0, 0);
            float4 fa = make_float4(bf_lo(u.x), bf_hi(u.x), bf_lo(u.y), bf_hi(u.y));
            float4 fb = make_float4(bf_lo(u.z), bf_hi(u.z), bf_lo(u.w), bf_hi(u.w));
            sX[rowin * 32 + (d & 15) * 2]     = fa;
            sX[rowin * 32 + (d & 15) * 2 + 1] = fb;
        } else {
            const float4* A4 = (const float4*)Ain;
            const int base = tile * 256;
            const int rem4 = nrows * 32 - base;
            sX[d]       = (d < rem4)       ? A4[base + d]       : make_float4(0.f, 0.f, 0.f, 0.f);
            sX[d + 128] = (d + 128 < rem4) ? A4[base + d + 128] : make_float4(0.f, 0.f, 0.f, 0.f);
        }
        __syncthreads();
#pragma unroll
        for (int n = 0; n < 8; ++n) {
            const int rowi = tile * 8 + n;
            float acc = b;
#pragma unroll
            for (int k4 = 0; k4 < 32; ++k4) {
                float4 xv = sX[n * 32 + k4];
                acc = fmaf(xv.x, w[4 * k4 + 0], acc);
                acc = fmaf(xv.y, w[4 * k4 + 1], acc);
                acc = fmaf(xv.z, w[4 * k4 + 2], acc);
                acc = fmaf(xv.w, w[4 * k4 + 3], acc);
            }
            if (rowi < nrows) out[(size_t)rowi * D + d] = f2bf(acc);
        }
        __syncthreads();
    }
}

// ---------- kernel 3: histogram of rows ----------
__global__ void hist_rows(const int* __restrict__ ei, int E, int* __restrict__ cnt) {
    int i = blockIdx.x * blockDim.x + threadIdx.x;
    if (i < E) atomicAdd(&cnt[ei[i]], 1);
}

// ---------- kernel 4: multi-block scan; block base via atomic cursor ----------
__global__ __launch_bounds__(1024)
void scan_block_atomic(const int* __restrict__ cnt, int* __restrict__ start,
                       int* __restrict__ cursor, int n) {
    __shared__ int wsum[16];
    __shared__ int sbase;
    const int tid = threadIdx.x, lane = tid & 63, wid = tid >> 6;
    const int i = blockIdx.x * 1024 + tid;
    const int v = (i < n) ? cnt[i] : 0;
    int x = v;
#pragma unroll
    for (int off = 1; off < 64; off <<= 1) {
        int t = __shfl_up(x, off);
        if (lane >= off) x += t;
    }
    if (lane == 63) wsum[wid] = x;
    __syncthreads();
    if (wid == 0) {
        int w = (lane < 16) ? wsum[lane] : 0;
#pragma unroll
        for (int off = 1; off < 16; off <<= 1) {
            int t = __shfl_up(w, off);
            if (lane >= off) w += t;
        }
        if (lane < 16) wsum[lane] = w;
    }
    __syncthreads();
    const int total = wsum[15];
    if (tid == 0) sbase = atomicAdd(cursor, total);
    __syncthreads();
    const int woff = (wid > 0) ? wsum[wid - 1] : 0;
    if (i < n) start[i] = sbase + woff + x - v;
}

// ---------- kernel 5: scatter (eid, col) pairs into CSR order ----------
__global__ void scatter_perm(const int* __restrict__ ei, int E,
                             const int* __restrict__ start, int* __restrict__ cur,
                             int2* __restrict__ perm2) {
    int e = blockIdx.x * blockDim.x + threadIdx.x;
    if (e < E) {
        int row = ei[e];
        int col = ei[E + e];
        int pos = start[row] + atomicAdd(&cur[row], 1);
        perm2[pos] = make_int2(e, col);
    }
}

// ---------- kernel 6: per-node gather-aggregate + residual + LayerNorm ----------
// One wave per node; lane holds dims (2l, 2l+1); depth-8 gather pipeline.
__global__ __launch_bounds__(256)
void aggregate_ln(const unsigned* __restrict__ h, const float* __restrict__ ea,
                  const int* __restrict__ start, const int* __restrict__ cnt,
                  const int2* __restrict__ perm2,
                  const float* __restrict__ Wc, const float* __restrict__ bc,
                  const unsigned* __restrict__ xtb,
                  const float* __restrict__ gamma, const float* __restrict__ beta,
                  float* __restrict__ out, int nnode) {
    const int lane = threadIdx.x & 63;
    const int wid = threadIdx.x >> 6;

    float2 wc[EDGE_DIM];
#pragma unroll
    for (int k = 0; k < EDGE_DIM; ++k)
        wc[k] = reinterpret_cast<const float2*>(Wc)[k * 64 + lane];
    const float2 bc2 = reinterpret_cast<const float2*>(bc)[lane];
    const float2 g = reinterpret_cast<const float2*>(gamma)[lane];
    const float2 bb = reinterpret_cast<const float2*>(beta)[lane];

    for (int n = blockIdx.x * 4 + wid; n < nnode; n += gridDim.x * 4) {
        const int s = start[n];
        const int c = cnt[n];
        float ax = 0.f, ay = 0.f;
        for (int ibase = 0; ibase < c; ibase += 64) {
            const int m = min(64, c - ibase);
            int eid = 0, colv = 0;
            if (lane < m) {
                int2 pc = perm2[s + ibase + lane];
                eid = pc.x;
                colv = pc.y;
            }
            // colv defaults to 0 for inactive lanes -> overrun loads hit h[lane]: safe.
            auto LDH = [&](int j) -> unsigned {
                return h[(unsigned)(__shfl(colv, j) * 64 + lane)];
            };
            auto COMP = [&](int j, unsigned hv) {
                const int e = __builtin_amdgcn_readfirstlane(__shfl(eid, j));
                const float* ep = ea + (size_t)e * EDGE_DIM;  // uniform -> s_load
                const float e0 = ep[0], e1 = ep[1], e2 = ep[2];
                const float e3 = ep[3], e4 = ep[4], e5 = ep[5];
                float vx = bc2.x + bf_lo(hv);
                float vy = bc2.y + bf_hi(hv);
                vx = fmaf(e0, wc[0].x, vx); vy = fmaf(e0, wc[0].y, vy);
                vx = fmaf(e1, wc[1].x, vx); vy = fmaf(e1, wc[1].y, vy);
                vx = fmaf(e2, wc[2].x, vx); vy = fmaf(e2, wc[2].y, vy);
                vx = fmaf(e3, wc[3].x, vx); vy = fmaf(e3, wc[3].y, vy);
                vx = fmaf(e4, wc[4].x, vx); vy = fmaf(e4, wc[4].y, vy);
                vx = fmaf(e5, wc[5].x, vx); vy = fmaf(e5, wc[5].y, vy);
                ax += fmaxf(vx, 0.f);
                ay += fmaxf(vy, 0.f);
            };
            unsigned h0 = LDH(0), h1 = LDH(1), h2 = LDH(2), h3 = LDH(3),
                     h4 = LDH(4), h5 = LDH(5), h6 = LDH(6), h7 = LDH(7);
            int i = 0;
            for (; i + 8 <= m; i += 8) {
                COMP(i + 0, h0); h0 = LDH(i + 8);
                COMP(i + 1, h1); h1 = LDH(i + 9);
                COMP(i + 2, h2); h2 = LDH(i + 10);
                COMP(i + 3, h3); h3 = LDH(i + 11);
                COMP(i + 4, h4); h4 = LDH(i + 12);
                COMP(i + 5, h5); h5 = LDH(i + 13);
                COMP(i + 6, h6); h6 = LDH(i + 14);
                COMP(i + 7, h7); h7 = LDH(i + 15);
            }
            if (i + 0 < m) COMP(i + 0, h0);
            if (i + 1 < m) COMP(i + 1, h1);
            if (i + 2 < m) COMP(i + 2, h2);
            if (i + 3 < m) COMP(i + 3, h3);
            if (i + 4 < m) COMP(i + 4, h4);
            if (i + 5 < m) COMP(i + 5, h5);
            if (i + 6 < m) COMP(i + 6, h6);
        }
        const float inv = 1.0f / fmaxf((float)c, 1.0f);
        const unsigned xu = xtb[(unsigned)(n * 64 + lane)];
        float o0 = fmaf(ax, inv, bf_lo(xu));
        float o1 = fmaf(ay, inv, bf_hi(xu));
        float s1 = o0 + o1, s2 = o0 * o0 + o1 * o1;
#pragma unroll
        for (int off = 32; off; off >>= 1) {
            s1 += __shfl_xor(s1, off);
            s2 += __shfl_xor(s2, off);
        }
        const float mean = s1 * (1.0f / D);
        const float var = s2 * (1.0f / D) - mean * mean;
        const float rstd = rsqrtf(var + LN_EPS);
        float2 r;
        r.x = (o0 - mean) * rstd * g.x + bb.x;
        r.y = (o1 - mean) * rstd * g.y + bb.y;
        reinterpret_cast<float2*>(out)[(size_t)n * 64 + lane] = r;
    }
}

extern "C" void kernel_launch(void* const* d_in, const int* in_sizes, int n_in,
                              void* d_out, int out_size, void* d_ws, size_t ws_size,
                              hipStream_t stream) {
    const float* x     = (const float*)d_in[0];
    const float* eattr = (const float*)d_in[1];
    const float* Wn    = (const float*)d_in[2];
    const float* bn    = (const float*)d_in[3];
    const float* We    = (const float*)d_in[4];
    const float* be    = (const float*)d_in[5];
    const float* Wm    = (const float*)d_in[6];
    const float* bm    = (const float*)d_in[7];
    const float* gamma = (const float*)d_in[8];
    const float* beta  = (const float*)d_in[9];
    const int*   ei    = (const int*)d_in[10];

    const int N = in_sizes[0] / D;
    const int E = in_sizes[10] / 2;

    char* ws = (char*)d_ws;
    unsigned short* xtb = (unsigned short*)ws; ws += (size_t)N * D * 2;
    unsigned short* hb  = (unsigned short*)ws; ws += (size_t)N * D * 2;
    int* ints = (int*)ws;                      ws += (size_t)(2 * N + 4) * 4;
    int* cnt = ints;
    int* cur = ints + N;
    int* cursor = ints + 2 * N;
    int* startv = (int*)ws;                    ws += (size_t)N * 4;
    int2* perm2 = (int2*)ws;                   ws += (size_t)E * 8;
    float* Wc = (float*)ws;                    ws += (size_t)EDGE_DIM * D * 4;
    float* bcv = (float*)ws;                   ws += (size_t)D * 4;

    hipMemsetAsync(ints, 0, (size_t)(2 * N + 4) * 4, stream);

    prep_wc<<<1, 1024, 0, stream>>>(We, be, Wm, bm, Wc, bcv);
    gemm128<false><<<2048, 128, 0, stream>>>(x, Wn, bn, xtb, N);        // xt (bf16)
    gemm128<true><<<2048, 128, 0, stream>>>(xtb, Wm, nullptr, hb, N);   // h = xt@Wm1 (bf16)
    hist_rows<<<(E + 255) / 256, 256, 0, stream>>>(ei, E, cnt);
    scan_block_atomic<<<(N + 1023) / 1024, 1024, 0, stream>>>(cnt, startv, cursor, N);
    scatter_perm<<<(E + 255) / 256, 256, 0, stream>>>(ei, E, startv, cur, perm2);
    aggregate_ln<<<(N + 3) / 4, 256, 0, stream>>>((const unsigned*)hb, eattr, startv, cnt,
                                                  perm2, Wc, bcv, (const unsigned*)xtb,
                                                  gamma, beta, (float*)d_out, N);
}

// Round 5
// 238.453 us; speedup vs baseline: 1.1335x; 1.1335x over previous
//
#include <hip/hip_runtime.h>
#include <hip/hip_bf16.h>

#define D 128
#define EDGE_DIM 6
#define LN_EPS 1e-5f

static __device__ __forceinline__ float bf_lo(unsigned u) { return __uint_as_float(u << 16); }
static __device__ __forceinline__ float bf_hi(unsigned u) { return __uint_as_float(u & 0xffff0000u); }
static __device__ __forceinline__ unsigned short f2bf(float f) {
    __hip_bfloat16 h = __float2bfloat16(f);
    return *reinterpret_cast<unsigned short*>(&h);
}

// ---------- kernel 1: Wc = We @ Wm2, bc = be @ Wm2 + bm (8 waves) ----------
__global__ __launch_bounds__(1024)
void prep_wc(const float* __restrict__ We, const float* __restrict__ be,
             const float* __restrict__ Wm, const float* __restrict__ bm,
             float* __restrict__ Wc, float* __restrict__ bc) {
    const int d = threadIdx.x & (D - 1);
    const int grp = threadIdx.x >> 7;  // 0..7
    __shared__ float sred[7][8][D];
    float acc[EDGE_DIM] = {0.f, 0.f, 0.f, 0.f, 0.f, 0.f};
    float accb = 0.f;
    for (int j = grp * 16; j < grp * 16 + 16; ++j) {
        float wm2 = Wm[(D + j) * D + d];
        accb = fmaf(be[j], wm2, accb);
#pragma unroll
        for (int k = 0; k < EDGE_DIM; ++k)
            acc[k] = fmaf(We[k * D + j], wm2, acc[k]);
    }
#pragma unroll
    for (int k = 0; k < EDGE_DIM; ++k) sred[k][grp][d] = acc[k];
    sred[6][grp][d] = accb;
    __syncthreads();
    if (threadIdx.x < D) {
#pragma unroll
        for (int k = 0; k < EDGE_DIM; ++k) {
            float s = 0.f;
#pragma unroll
            for (int g = 0; g < 8; ++g) s += sred[k][g][d];
            Wc[k * D + d] = s;
        }
        float s = 0.f;
#pragma unroll
        for (int g = 0; g < 8; ++g) s += sred[6][g][d];
        bc[d] = s + bm[d];
    }
}

// ---------- kernel 2: out_bf16[n][d] = bias[d] + sum_k A[n][k] * W[k][d] ----------
template <bool A_BF16>
__global__ __launch_bounds__(128)
void gemm128(const void* __restrict__ Ain, const float* __restrict__ W,
             const float* __restrict__ bias, unsigned short* __restrict__ out, int nrows) {
    const int d = threadIdx.x;
    float w[D];
#pragma unroll
    for (int k = 0; k < D; ++k) w[k] = W[k * D + d];
    const float b = bias ? bias[d] : 0.0f;

    __shared__ float4 sX[8 * 32];
    const int ntiles = (nrows + 7) / 8;

    for (int tile = blockIdx.x; tile < ntiles; tile += gridDim.x) {
        if (A_BF16) {
            const uint4* A16 = (const uint4*)Ain;  // 8 bf16 per uint4
            const int rowin = d >> 4;
            uint4 u = (tile * 8 + rowin < nrows) ? A16[(size_t)tile * 128 + d]
                                                 : make_uint4(0, 0, 0, 0);
            float4 fa = make_float4(bf_lo(u.x), bf_hi(u.x), bf_lo(u.y), bf_hi(u.y));
            float4 fb = make_float4(bf_lo(u.z), bf_hi(u.z), bf_lo(u.w), bf_hi(u.w));
            sX[rowin * 32 + (d & 15) * 2]     = fa;
            sX[rowin * 32 + (d & 15) * 2 + 1] = fb;
        } else {
            const float4* A4 = (const float4*)Ain;
            const int base = tile * 256;
            const int rem4 = nrows * 32 - base;
            sX[d]       = (d < rem4)       ? A4[base + d]       : make_float4(0.f, 0.f, 0.f, 0.f);
            sX[d + 128] = (d + 128 < rem4) ? A4[base + d + 128] : make_float4(0.f, 0.f, 0.f, 0.f);
        }
        __syncthreads();
#pragma unroll
        for (int n = 0; n < 8; ++n) {
            const int rowi = tile * 8 + n;
            float acc = b;
#pragma unroll
            for (int k4 = 0; k4 < 32; ++k4) {
                float4 xv = sX[n * 32 + k4];
                acc = fmaf(xv.x, w[4 * k4 + 0], acc);
                acc = fmaf(xv.y, w[4 * k4 + 1], acc);
                acc = fmaf(xv.z, w[4 * k4 + 2], acc);
                acc = fmaf(xv.w, w[4 * k4 + 3], acc);
            }
            if (rowi < nrows) out[(size_t)rowi * D + d] = f2bf(acc);
        }
        __syncthreads();
    }
}

// ---------- kernel 3: histogram of rows ----------
__global__ void hist_rows(const int* __restrict__ ei, int E, int* __restrict__ cnt) {
    int i = blockIdx.x * blockDim.x + threadIdx.x;
    if (i < E) atomicAdd(&cnt[ei[i]], 1);
}

// ---------- kernel 4: multi-block scan; block base via atomic cursor ----------
__global__ __launch_bounds__(1024)
void scan_block_atomic(const int* __restrict__ cnt, int* __restrict__ start,
                       int* __restrict__ cursor, int n) {
    __shared__ int wsum[16];
    __shared__ int sbase;
    const int tid = threadIdx.x, lane = tid & 63, wid = tid >> 6;
    const int i = blockIdx.x * 1024 + tid;
    const int v = (i < n) ? cnt[i] : 0;
    int x = v;
#pragma unroll
    for (int off = 1; off < 64; off <<= 1) {
        int t = __shfl_up(x, off);
        if (lane >= off) x += t;
    }
    if (lane == 63) wsum[wid] = x;
    __syncthreads();
    if (wid == 0) {
        int w = (lane < 16) ? wsum[lane] : 0;
#pragma unroll
        for (int off = 1; off < 16; off <<= 1) {
            int t = __shfl_up(w, off);
            if (lane >= off) w += t;
        }
        if (lane < 16) wsum[lane] = w;
    }
    __syncthreads();
    const int total = wsum[15];
    if (tid == 0) sbase = atomicAdd(cursor, total);
    __syncthreads();
    const int woff = (wid > 0) ? wsum[wid - 1] : 0;
    if (i < n) start[i] = sbase + woff + x - v;
}

// ---------- kernel 5: scatter CSR records (col, ea as 6xbf16) = 16B/edge ----------
__global__ void scatter_rec(const int* __restrict__ ei, int E, const float* __restrict__ ea,
                            const int* __restrict__ start, int* __restrict__ cur,
                            uint4* __restrict__ rec) {
    int e = blockIdx.x * blockDim.x + threadIdx.x;
    if (e < E) {
        int row = ei[e];
        int col = ei[E + e];
        const float* ep = ea + (size_t)e * EDGE_DIM;
        unsigned b01 = (unsigned)f2bf(ep[0]) | ((unsigned)f2bf(ep[1]) << 16);
        unsigned b23 = (unsigned)f2bf(ep[2]) | ((unsigned)f2bf(ep[3]) << 16);
        unsigned b45 = (unsigned)f2bf(ep[4]) | ((unsigned)f2bf(ep[5]) << 16);
        int pos = start[row] + atomicAdd(&cur[row], 1);
        rec[pos] = make_uint4((unsigned)col, b01, b23, b45);
    }
}

// ---------- kernel 6: per-node gather-aggregate + residual + LayerNorm ----------
// One wave per node; lane holds dims (2l, 2l+1). Per edge: 4 readlane broadcasts
// from the streamed record + one pipelined 256B h-gather. No other per-edge mem ops.
__global__ __launch_bounds__(256)
void aggregate_ln(const unsigned* __restrict__ h,
                  const int* __restrict__ start, const int* __restrict__ cnt,
                  const uint4* __restrict__ rec,
                  const float* __restrict__ Wc, const float* __restrict__ bc,
                  const unsigned* __restrict__ xtb,
                  const float* __restrict__ gamma, const float* __restrict__ beta,
                  float* __restrict__ out, int nnode) {
    const int lane = threadIdx.x & 63;
    const int wid = threadIdx.x >> 6;

    float2 wc[EDGE_DIM];
#pragma unroll
    for (int k = 0; k < EDGE_DIM; ++k)
        wc[k] = reinterpret_cast<const float2*>(Wc)[k * 64 + lane];
    const float2 bc2 = reinterpret_cast<const float2*>(bc)[lane];
    const float2 g = reinterpret_cast<const float2*>(gamma)[lane];
    const float2 bb = reinterpret_cast<const float2*>(beta)[lane];

    for (int n = blockIdx.x * 4 + wid; n < nnode; n += gridDim.x * 4) {
        const int s = start[n];
        const int c = cnt[n];
        float ax = 0.f, ay = 0.f;
        for (int ibase = 0; ibase < c; ibase += 64) {
            const int m = min(64, c - ibase);
            uint4 rc = make_uint4(0, 0, 0, 0);
            if (lane < m) rc = rec[(size_t)(s + ibase) + lane];
            // Prefetch index clamped to m-1: overrun prefetches collapse to one
            // repeated (L1-hit) address instead of stray gathers.
            auto LDH = [&](int j) -> unsigned {
                const int jc = min(j, m - 1);
                const int colj = __builtin_amdgcn_readlane((int)rc.x, jc);
                return h[(unsigned)(colj * 64 + lane)];
            };
            auto COMP = [&](int j, unsigned hv) {
                const unsigned b01 = (unsigned)__builtin_amdgcn_readlane((int)rc.y, j);
                const unsigned b23 = (unsigned)__builtin_amdgcn_readlane((int)rc.z, j);
                const unsigned b45 = (unsigned)__builtin_amdgcn_readlane((int)rc.w, j);
                const float e0 = bf_lo(b01), e1 = bf_hi(b01);
                const float e2 = bf_lo(b23), e3 = bf_hi(b23);
                const float e4 = bf_lo(b45), e5 = bf_hi(b45);
                float vx = bc2.x + bf_lo(hv);
                float vy = bc2.y + bf_hi(hv);
                vx = fmaf(e0, wc[0].x, vx); vy = fmaf(e0, wc[0].y, vy);
                vx = fmaf(e1, wc[1].x, vx); vy = fmaf(e1, wc[1].y, vy);
                vx = fmaf(e2, wc[2].x, vx); vy = fmaf(e2, wc[2].y, vy);
                vx = fmaf(e3, wc[3].x, vx); vy = fmaf(e3, wc[3].y, vy);
                vx = fmaf(e4, wc[4].x, vx); vy = fmaf(e4, wc[4].y, vy);
                vx = fmaf(e5, wc[5].x, vx); vy = fmaf(e5, wc[5].y, vy);
                ax += fmaxf(vx, 0.f);
                ay += fmaxf(vy, 0.f);
            };
            unsigned h0 = LDH(0), h1 = LDH(1), h2 = LDH(2), h3 = LDH(3),
                     h4 = LDH(4), h5 = LDH(5), h6 = LDH(6), h7 = LDH(7);
            int i = 0;
            for (; i + 8 <= m; i += 8) {
                COMP(i + 0, h0); h0 = LDH(i + 8);
                COMP(i + 1, h1); h1 = LDH(i + 9);
                COMP(i + 2, h2); h2 = LDH(i + 10);
                COMP(i + 3, h3); h3 = LDH(i + 11);
                COMP(i + 4, h4); h4 = LDH(i + 12);
                COMP(i + 5, h5); h5 = LDH(i + 13);
                COMP(i + 6, h6); h6 = LDH(i + 14);
                COMP(i + 7, h7); h7 = LDH(i + 15);
            }
            if (i + 0 < m) COMP(i + 0, h0);
            if (i + 1 < m) COMP(i + 1, h1);
            if (i + 2 < m) COMP(i + 2, h2);
            if (i + 3 < m) COMP(i + 3, h3);
            if (i + 4 < m) COMP(i + 4, h4);
            if (i + 5 < m) COMP(i + 5, h5);
            if (i + 6 < m) COMP(i + 6, h6);
        }
        const float inv = 1.0f / fmaxf((float)c, 1.0f);
        const unsigned xu = xtb[(unsigned)(n * 64 + lane)];
        float o0 = fmaf(ax, inv, bf_lo(xu));
        float o1 = fmaf(ay, inv, bf_hi(xu));
        float s1 = o0 + o1, s2 = o0 * o0 + o1 * o1;
#pragma unroll
        for (int off = 32; off; off >>= 1) {
            s1 += __shfl_xor(s1, off);
            s2 += __shfl_xor(s2, off);
        }
        const float mean = s1 * (1.0f / D);
        const float var = s2 * (1.0f / D) - mean * mean;
        const float rstd = rsqrtf(var + LN_EPS);
        float2 r;
        r.x = (o0 - mean) * rstd * g.x + bb.x;
        r.y = (o1 - mean) * rstd * g.y + bb.y;
        reinterpret_cast<float2*>(out)[(size_t)n * 64 + lane] = r;
    }
}

extern "C" void kernel_launch(void* const* d_in, const int* in_sizes, int n_in,
                              void* d_out, int out_size, void* d_ws, size_t ws_size,
                              hipStream_t stream) {
    const float* x     = (const float*)d_in[0];
    const float* eattr = (const float*)d_in[1];
    const float* Wn    = (const float*)d_in[2];
    const float* bn    = (const float*)d_in[3];
    const float* We    = (const float*)d_in[4];
    const float* be    = (const float*)d_in[5];
    const float* Wm    = (const float*)d_in[6];
    const float* bm    = (const float*)d_in[7];
    const float* gamma = (const float*)d_in[8];
    const float* beta  = (const float*)d_in[9];
    const int*   ei    = (const int*)d_in[10];

    const int N = in_sizes[0] / D;
    const int E = in_sizes[10] / 2;

    char* ws = (char*)d_ws;
    unsigned short* xtb = (unsigned short*)ws; ws += (size_t)N * D * 2;
    unsigned short* hb  = (unsigned short*)ws; ws += (size_t)N * D * 2;
    int* ints = (int*)ws;                      ws += (size_t)(2 * N + 4) * 4;
    int* cnt = ints;
    int* cur = ints + N;
    int* cursor = ints + 2 * N;
    int* startv = (int*)ws;                    ws += (size_t)N * 4;
    uint4* rec = (uint4*)ws;                   ws += (size_t)E * 16;
    float* Wc = (float*)ws;                    ws += (size_t)EDGE_DIM * D * 4;
    float* bcv = (float*)ws;                   ws += (size_t)D * 4;

    hipMemsetAsync(ints, 0, (size_t)(2 * N + 4) * 4, stream);

    prep_wc<<<1, 1024, 0, stream>>>(We, be, Wm, bm, Wc, bcv);
    gemm128<false><<<2048, 128, 0, stream>>>(x, Wn, bn, xtb, N);        // xt (bf16)
    gemm128<true><<<2048, 128, 0, stream>>>(xtb, Wm, nullptr, hb, N);   // h = xt@Wm1 (bf16)
    hist_rows<<<(E + 255) / 256, 256, 0, stream>>>(ei, E, cnt);
    scan_block_atomic<<<(N + 1023) / 1024, 1024, 0, stream>>>(cnt, startv, cursor, N);
    scatter_rec<<<(E + 255) / 256, 256, 0, stream>>>(ei, E, eattr, startv, cur, rec);
    aggregate_ln<<<(N + 3) / 4, 256, 0, stream>>>((const unsigned*)hb, startv, cnt, rec,
                                                  Wc, bcv, (const unsigned*)xtb,
                                                  gamma, beta, (float*)d_out, N);
}

// Round 6
// 218.537 us; speedup vs baseline: 1.2368x; 1.0911x over previous
//
#include <hip/hip_runtime.h>
#include <hip/hip_bf16.h>

#define D 128
#define EDGE_DIM 6
#define LN_EPS 1e-5f
#define HIST_BLOCKS 2048

static __device__ __forceinline__ float bf_lo(unsigned u) { return __uint_as_float(u << 16); }
static __device__ __forceinline__ float bf_hi(unsigned u) { return __uint_as_float(u & 0xffff0000u); }
static __device__ __forceinline__ unsigned short f2bf(float f) {
    __hip_bfloat16 h = __float2bfloat16(f);
    return *reinterpret_cast<unsigned short*>(&h);
}

// ---------- kernel 1: fused setup ----------
// blocks 0..127   : Wnm[b][d] = sum_j Wn[b][j] * Wm1[j][d]      (Wm rows 0..127)
// block  128      : bnm[d]    = sum_j bn[j]   * Wm1[j][d]
// blocks 129..134 : Wc[k][d]  = sum_j We[k][j] * Wm2[j][d]      (Wm rows 128..255)
// block  135      : bc[d]     = sum_j be[j]   * Wm2[j][d] + bm[d]
// blocks >=136    : histogram of edge rows into cnt
__global__ __launch_bounds__(128)
void setup_all(const float* __restrict__ Wn, const float* __restrict__ bn,
               const float* __restrict__ We, const float* __restrict__ be,
               const float* __restrict__ Wm, const float* __restrict__ bm,
               const int* __restrict__ ei, int E,
               float* __restrict__ Wnm, float* __restrict__ bnm,
               float* __restrict__ Wc, float* __restrict__ bc,
               int* __restrict__ cnt) {
    const int b = blockIdx.x;
    const int d = threadIdx.x;
    if (b < 128) {
        float acc = 0.f;
#pragma unroll 8
        for (int j = 0; j < D; ++j)
            acc = fmaf(Wn[b * D + j], Wm[j * D + d], acc);
        Wnm[b * D + d] = acc;
    } else if (b == 128) {
        float acc = 0.f;
#pragma unroll 8
        for (int j = 0; j < D; ++j)
            acc = fmaf(bn[j], Wm[j * D + d], acc);
        bnm[d] = acc;
    } else if (b < 135) {
        const int k = b - 129;
        float acc = 0.f;
#pragma unroll 8
        for (int j = 0; j < D; ++j)
            acc = fmaf(We[k * D + j], Wm[(D + j) * D + d], acc);
        Wc[k * D + d] = acc;
    } else if (b == 135) {
        float acc = bm[d];
#pragma unroll 8
        for (int j = 0; j < D; ++j)
            acc = fmaf(be[j], Wm[(D + j) * D + d], acc);
        bc[d] = acc;
    } else {
        for (int i = (b - 136) * 128 + d; i < E; i += HIST_BLOCKS * 128)
            atomicAdd(&cnt[ei[i]], 1);
    }
}

// ---------- kernel 2: dual GEMM from one x pass ----------
// threads 0..127:  xtb[n][d] = bn[d]  + sum_k x[n][k]*Wn[k][d]   (bf16 out)
// threads 128..255: hb[n][d] = bnm[d] + sum_k x[n][k]*Wnm[k][d]  (bf16 out)
__global__ __launch_bounds__(256)
void gemm_dual(const float* __restrict__ x,
               const float* __restrict__ Wn, const float* __restrict__ bn,
               const float* __restrict__ Wnm, const float* __restrict__ bnm,
               unsigned short* __restrict__ xtb, unsigned short* __restrict__ hb,
               int nrows) {
    const int tid = threadIdx.x;
    const int d = tid & (D - 1);
    const bool hi = tid >= D;
    const float* W = hi ? Wnm : Wn;
    float w[D];
#pragma unroll
    for (int k = 0; k < D; ++k) w[k] = W[k * D + d];
    const float b = hi ? bnm[d] : bn[d];
    unsigned short* out = hi ? hb : xtb;

    __shared__ float4 sX[256];  // 8 rows x 128 floats
    const float4* A4 = reinterpret_cast<const float4*>(x);
    const int ntiles = (nrows + 7) / 8;

    for (int tile = blockIdx.x; tile < ntiles; tile += gridDim.x) {
        const int base = tile * 256;
        const int rem4 = nrows * 32 - base;
        sX[tid] = (tid < rem4) ? A4[base + tid] : make_float4(0.f, 0.f, 0.f, 0.f);
        __syncthreads();
#pragma unroll
        for (int n = 0; n < 8; ++n) {
            const int rowi = tile * 8 + n;
            float acc = b;
#pragma unroll
            for (int k4 = 0; k4 < 32; ++k4) {
                float4 xv = sX[n * 32 + k4];
                acc = fmaf(xv.x, w[4 * k4 + 0], acc);
                acc = fmaf(xv.y, w[4 * k4 + 1], acc);
                acc = fmaf(xv.z, w[4 * k4 + 2], acc);
                acc = fmaf(xv.w, w[4 * k4 + 3], acc);
            }
            if (rowi < nrows) out[(size_t)rowi * D + d] = f2bf(acc);
        }
        __syncthreads();
    }
}

// ---------- kernel 3: multi-block scan; writes start AND cur (= start copy) ----------
__global__ __launch_bounds__(1024)
void scan_block_atomic(const int* __restrict__ cnt, int* __restrict__ start,
                       int* __restrict__ cur, int* __restrict__ cursor, int n) {
    __shared__ int wsum[16];
    __shared__ int sbase;
    const int tid = threadIdx.x, lane = tid & 63, wid = tid >> 6;
    const int i = blockIdx.x * 1024 + tid;
    const int v = (i < n) ? cnt[i] : 0;
    int x = v;
#pragma unroll
    for (int off = 1; off < 64; off <<= 1) {
        int t = __shfl_up(x, off);
        if (lane >= off) x += t;
    }
    if (lane == 63) wsum[wid] = x;
    __syncthreads();
    if (wid == 0) {
        int w = (lane < 16) ? wsum[lane] : 0;
#pragma unroll
        for (int off = 1; off < 16; off <<= 1) {
            int t = __shfl_up(w, off);
            if (lane >= off) w += t;
        }
        if (lane < 16) wsum[lane] = w;
    }
    __syncthreads();
    const int total = wsum[15];
    if (tid == 0) sbase = atomicAdd(cursor, total);
    __syncthreads();
    const int woff = (wid > 0) ? wsum[wid - 1] : 0;
    if (i < n) {
        const int sv = sbase + woff + x - v;
        start[i] = sv;
        cur[i] = sv;
    }
}

// ---------- kernel 4: scatter CSR records (col, ea as 6xbf16) = 16B/edge ----------
__global__ void scatter_rec(const int* __restrict__ ei, int E, const float* __restrict__ ea,
                            int* __restrict__ cur, uint4* __restrict__ rec) {
    int e = blockIdx.x * blockDim.x + threadIdx.x;
    if (e < E) {
        int row = ei[e];
        int col = ei[E + e];
        const float* ep = ea + (size_t)e * EDGE_DIM;
        unsigned b01 = (unsigned)f2bf(ep[0]) | ((unsigned)f2bf(ep[1]) << 16);
        unsigned b23 = (unsigned)f2bf(ep[2]) | ((unsigned)f2bf(ep[3]) << 16);
        unsigned b45 = (unsigned)f2bf(ep[4]) | ((unsigned)f2bf(ep[5]) << 16);
        int pos = atomicAdd(&cur[row], 1);  // cur pre-initialized to start
        rec[pos] = make_uint4((unsigned)col, b01, b23, b45);
    }
}

// ---------- kernel 5: per-node gather-aggregate + residual + LayerNorm ----------
__global__ __launch_bounds__(256)
void aggregate_ln(const unsigned* __restrict__ h,
                  const int* __restrict__ start, const int* __restrict__ cnt,
                  const uint4* __restrict__ rec,
                  const float* __restrict__ Wc, const float* __restrict__ bc,
                  const unsigned* __restrict__ xtb,
                  const float* __restrict__ gamma, const float* __restrict__ beta,
                  float* __restrict__ out, int nnode) {
    const int lane = threadIdx.x & 63;
    const int wid = threadIdx.x >> 6;

    float2 wc[EDGE_DIM];
#pragma unroll
    for (int k = 0; k < EDGE_DIM; ++k)
        wc[k] = reinterpret_cast<const float2*>(Wc)[k * 64 + lane];
    const float2 bc2 = reinterpret_cast<const float2*>(bc)[lane];
    const float2 g = reinterpret_cast<const float2*>(gamma)[lane];
    const float2 bb = reinterpret_cast<const float2*>(beta)[lane];

    for (int n = blockIdx.x * 4 + wid; n < nnode; n += gridDim.x * 4) {
        const int s = start[n];
        const int c = cnt[n];
        float ax = 0.f, ay = 0.f;
        for (int ibase = 0; ibase < c; ibase += 64) {
            const int m = min(64, c - ibase);
            uint4 rc = make_uint4(0, 0, 0, 0);
            if (lane < m) rc = rec[(size_t)(s + ibase) + lane];
            auto LDH = [&](int j) -> unsigned {
                const int jc = min(j, m - 1);
                const int colj = __builtin_amdgcn_readlane((int)rc.x, jc);
                return h[(unsigned)(colj * 64 + lane)];
            };
            auto COMP = [&](int j, unsigned hv) {
                const unsigned b01 = (unsigned)__builtin_amdgcn_readlane((int)rc.y, j);
                const unsigned b23 = (unsigned)__builtin_amdgcn_readlane((int)rc.z, j);
                const unsigned b45 = (unsigned)__builtin_amdgcn_readlane((int)rc.w, j);
                const float e0 = bf_lo(b01), e1 = bf_hi(b01);
                const float e2 = bf_lo(b23), e3 = bf_hi(b23);
                const float e4 = bf_lo(b45), e5 = bf_hi(b45);
                float vx = bc2.x + bf_lo(hv);
                float vy = bc2.y + bf_hi(hv);
                vx = fmaf(e0, wc[0].x, vx); vy = fmaf(e0, wc[0].y, vy);
                vx = fmaf(e1, wc[1].x, vx); vy = fmaf(e1, wc[1].y, vy);
                vx = fmaf(e2, wc[2].x, vx); vy = fmaf(e2, wc[2].y, vy);
                vx = fmaf(e3, wc[3].x, vx); vy = fmaf(e3, wc[3].y, vy);
                vx = fmaf(e4, wc[4].x, vx); vy = fmaf(e4, wc[4].y, vy);
                vx = fmaf(e5, wc[5].x, vx); vy = fmaf(e5, wc[5].y, vy);
                ax += fmaxf(vx, 0.f);
                ay += fmaxf(vy, 0.f);
            };
            unsigned h0 = LDH(0), h1 = LDH(1), h2 = LDH(2), h3 = LDH(3),
                     h4 = LDH(4), h5 = LDH(5), h6 = LDH(6), h7 = LDH(7);
            int i = 0;
            for (; i + 8 <= m; i += 8) {
                COMP(i + 0, h0); h0 = LDH(i + 8);
                COMP(i + 1, h1); h1 = LDH(i + 9);
                COMP(i + 2, h2); h2 = LDH(i + 10);
                COMP(i + 3, h3); h3 = LDH(i + 11);
                COMP(i + 4, h4); h4 = LDH(i + 12);
                COMP(i + 5, h5); h5 = LDH(i + 13);
                COMP(i + 6, h6); h6 = LDH(i + 14);
                COMP(i + 7, h7); h7 = LDH(i + 15);
            }
            if (i + 0 < m) COMP(i + 0, h0);
            if (i + 1 < m) COMP(i + 1, h1);
            if (i + 2 < m) COMP(i + 2, h2);
            if (i + 3 < m) COMP(i + 3, h3);
            if (i + 4 < m) COMP(i + 4, h4);
            if (i + 5 < m) COMP(i + 5, h5);
            if (i + 6 < m) COMP(i + 6, h6);
        }
        const float inv = 1.0f / fmaxf((float)c, 1.0f);
        const unsigned xu = xtb[(unsigned)(n * 64 + lane)];
        float o0 = fmaf(ax, inv, bf_lo(xu));
        float o1 = fmaf(ay, inv, bf_hi(xu));
        float s1 = o0 + o1, s2 = o0 * o0 + o1 * o1;
#pragma unroll
        for (int off = 32; off; off >>= 1) {
            s1 += __shfl_xor(s1, off);
            s2 += __shfl_xor(s2, off);
        }
        const float mean = s1 * (1.0f / D);
        const float var = s2 * (1.0f / D) - mean * mean;
        const float rstd = rsqrtf(var + LN_EPS);
        float2 r;
        r.x = (o0 - mean) * rstd * g.x + bb.x;
        r.y = (o1 - mean) * rstd * g.y + bb.y;
        reinterpret_cast<float2*>(out)[(size_t)n * 64 + lane] = r;
    }
}

extern "C" void kernel_launch(void* const* d_in, const int* in_sizes, int n_in,
                              void* d_out, int out_size, void* d_ws, size_t ws_size,
                              hipStream_t stream) {
    const float* x     = (const float*)d_in[0];
    const float* eattr = (const float*)d_in[1];
    const float* Wn    = (const float*)d_in[2];
    const float* bn    = (const float*)d_in[3];
    const float* We    = (const float*)d_in[4];
    const float* be    = (const float*)d_in[5];
    const float* Wm    = (const float*)d_in[6];
    const float* bm    = (const float*)d_in[7];
    const float* gamma = (const float*)d_in[8];
    const float* beta  = (const float*)d_in[9];
    const int*   ei    = (const int*)d_in[10];

    const int N = in_sizes[0] / D;
    const int E = in_sizes[10] / 2;

    char* ws = (char*)d_ws;
    unsigned short* xtb = (unsigned short*)ws; ws += (size_t)N * D * 2;
    unsigned short* hb  = (unsigned short*)ws; ws += (size_t)N * D * 2;
    int* ints = (int*)ws;                      ws += (size_t)(N + 4) * 4;  // cnt, cursor
    int* cnt = ints;
    int* cursor = ints + N;
    int* cur    = (int*)ws;                    ws += (size_t)N * 4;
    int* startv = (int*)ws;                    ws += (size_t)N * 4;
    uint4* rec  = (uint4*)ws;                  ws += (size_t)E * 16;
    float* Wnm  = (float*)ws;                  ws += (size_t)D * D * 4;
    float* bnm  = (float*)ws;                  ws += (size_t)D * 4;
    float* Wc   = (float*)ws;                  ws += (size_t)EDGE_DIM * D * 4;
    float* bcv  = (float*)ws;                  ws += (size_t)D * 4;

    hipMemsetAsync(ints, 0, (size_t)(N + 4) * 4, stream);

    setup_all<<<136 + HIST_BLOCKS, 128, 0, stream>>>(Wn, bn, We, be, Wm, bm, ei, E,
                                                     Wnm, bnm, Wc, bcv, cnt);
    scan_block_atomic<<<(N + 1023) / 1024, 1024, 0, stream>>>(cnt, startv, cur, cursor, N);
    scatter_rec<<<(E + 255) / 256, 256, 0, stream>>>(ei, E, eattr, cur, rec);
    gemm_dual<<<2048, 256, 0, stream>>>(x, Wn, bn, Wnm, bnm, xtb, hb, N);
    aggregate_ln<<<(N + 3) / 4, 256, 0, stream>>>((const unsigned*)hb, startv, cnt, rec,
                                                  Wc, bcv, (const unsigned*)xtb,
                                                  gamma, beta, (float*)d_out, N);
}

// Round 7
// 182.738 us; speedup vs baseline: 1.4791x; 1.1959x over previous
//
#include <hip/hip_runtime.h>
#include <hip/hip_bf16.h>

#define D 128
#define EDGE_DIM 6
#define LN_EPS 1e-5f
#define HIST_BLOCKS 2048

typedef __attribute__((ext_vector_type(8))) short short8;
typedef __attribute__((ext_vector_type(4))) float f32x4;

static __device__ __forceinline__ float bf_lo(unsigned u) { return __uint_as_float(u << 16); }
static __device__ __forceinline__ float bf_hi(unsigned u) { return __uint_as_float(u & 0xffff0000u); }
static __device__ __forceinline__ unsigned short f2bf(float f) {
    __hip_bfloat16 h = __float2bfloat16(f);
    return *reinterpret_cast<unsigned short*>(&h);
}

// ---------- kernel 1: fused setup ----------
// blocks 0..127   : Wnm[b][d] = sum_j Wn[b][j] * Wm1[j][d]
// block  128      : bnm[d]    = sum_j bn[j]   * Wm1[j][d]
// blocks 129..134 : Wc[k][d]  = sum_j We[k][j] * Wm2[j][d]
// block  135      : bc[d]     = sum_j be[j]   * Wm2[j][d] + bm[d]
// blocks >=136    : histogram of edge rows into cnt
__global__ __launch_bounds__(128)
void setup_all(const float* __restrict__ Wn, const float* __restrict__ bn,
               const float* __restrict__ We, const float* __restrict__ be,
               const float* __restrict__ Wm, const float* __restrict__ bm,
               const int* __restrict__ ei, int E,
               float* __restrict__ Wnm, float* __restrict__ bnm,
               float* __restrict__ Wc, float* __restrict__ bc,
               int* __restrict__ cnt) {
    const int b = blockIdx.x;
    const int d = threadIdx.x;
    if (b < 128) {
        float acc = 0.f;
#pragma unroll 8
        for (int j = 0; j < D; ++j)
            acc = fmaf(Wn[b * D + j], Wm[j * D + d], acc);
        Wnm[b * D + d] = acc;
    } else if (b == 128) {
        float acc = 0.f;
#pragma unroll 8
        for (int j = 0; j < D; ++j)
            acc = fmaf(bn[j], Wm[j * D + d], acc);
        bnm[d] = acc;
    } else if (b < 135) {
        const int k = b - 129;
        float acc = 0.f;
#pragma unroll 8
        for (int j = 0; j < D; ++j)
            acc = fmaf(We[k * D + j], Wm[(D + j) * D + d], acc);
        Wc[k * D + d] = acc;
    } else if (b == 135) {
        float acc = bm[d];
#pragma unroll 8
        for (int j = 0; j < D; ++j)
            acc = fmaf(be[j], Wm[(D + j) * D + d], acc);
        bc[d] = acc;
    } else {
        for (int i = (b - 136) * 128 + d; i < E; i += HIST_BLOCKS * 128)
            atomicAdd(&cnt[ei[i]], 1);
    }
}

// ---------- kernel 2: pack Wn/Wnm into MFMA B-fragment order (bf16) ----------
// Wb[(((mat*8+ct)*4+s)*64+lane)*8 + j] = W_mat[k][ct*16+(lane&15)], k=(lane>>4)*8+32s+j
__global__ __launch_bounds__(256)
void pack_wb(const float* __restrict__ Wn, const float* __restrict__ Wnm,
             unsigned short* __restrict__ Wb) {
    const int idx = blockIdx.x * 256 + threadIdx.x;  // 4096 fragments
    if (idx >= 4096) return;
    const int lane = idx & 63;
    const int s = (idx >> 6) & 3;
    const int ct = (idx >> 8) & 7;
    const int mat = idx >> 11;
    const float* W = mat ? Wnm : Wn;
    const int col = ct * 16 + (lane & 15);
    const int k0 = (lane >> 4) * 8 + 32 * s;
    short8 v;
#pragma unroll
    for (int j = 0; j < 8; ++j)
        v[j] = (short)f2bf(W[(size_t)(k0 + j) * D + col]);
    *reinterpret_cast<short8*>(Wb + (size_t)idx * 8) = v;
}

// ---------- kernel 3: dual MFMA GEMM, one x pass ----------
// wave handles 16 rows x 128 cols for BOTH mats: xtb = x@Wn+bn, hb = x@Wnm+bnm
__global__ __launch_bounds__(256)
void gemm_mfma(const float* __restrict__ x, const unsigned short* __restrict__ Wb,
               const float* __restrict__ bn, const float* __restrict__ bnm,
               unsigned short* __restrict__ xtb, unsigned short* __restrict__ hb,
               int nrows) {
    const int lane = threadIdx.x & 63;
    const int wid = threadIdx.x >> 6;
    const int row16 = lane & 15;
    const int kgrp = lane >> 4;  // 0..3
    const int ntile = (nrows + 15) / 16;

    float biasA[8], biasB[8];
#pragma unroll
    for (int ct = 0; ct < 8; ++ct) {
        biasA[ct] = bn[ct * 16 + row16];
        biasB[ct] = bnm[ct * 16 + row16];
    }

    for (int t = blockIdx.x * 4 + wid; t < ntile; t += gridDim.x * 4) {
        const int ra = t * 16 + row16;            // row this lane loads for A
        const bool rv = ra < nrows;
        short8 a[4];
#pragma unroll
        for (int s = 0; s < 4; ++s) {
            const float* xp = x + (size_t)ra * D + kgrp * 8 + 32 * s;
            float4 u0 = rv ? *reinterpret_cast<const float4*>(xp)
                           : make_float4(0.f, 0.f, 0.f, 0.f);
            float4 u1 = rv ? *reinterpret_cast<const float4*>(xp + 4)
                           : make_float4(0.f, 0.f, 0.f, 0.f);
            a[s][0] = (short)f2bf(u0.x); a[s][1] = (short)f2bf(u0.y);
            a[s][2] = (short)f2bf(u0.z); a[s][3] = (short)f2bf(u0.w);
            a[s][4] = (short)f2bf(u1.x); a[s][5] = (short)f2bf(u1.y);
            a[s][6] = (short)f2bf(u1.z); a[s][7] = (short)f2bf(u1.w);
        }
        const int rw0 = t * 16 + kgrp * 4;        // rows this lane writes
#pragma unroll
        for (int mat = 0; mat < 2; ++mat) {
            unsigned short* out = mat ? hb : xtb;
#pragma unroll
            for (int ct = 0; ct < 8; ++ct) {
                f32x4 acc = {0.f, 0.f, 0.f, 0.f};
#pragma unroll
                for (int s = 0; s < 4; ++s) {
                    short8 bfr = *reinterpret_cast<const short8*>(
                        Wb + (size_t)((((mat * 8 + ct) * 4 + s) * 64 + lane)) * 8);
                    acc = __builtin_amdgcn_mfma_f32_16x16x32_bf16(a[s], bfr, acc, 0, 0, 0);
                }
                const float bsc = mat ? biasB[ct] : biasA[ct];
                const int dcol = ct * 16 + row16;
#pragma unroll
                for (int j = 0; j < 4; ++j) {
                    const int r = rw0 + j;
                    if (r < nrows) out[(size_t)r * D + dcol] = f2bf(acc[j] + bsc);
                }
            }
        }
    }
}

// ---------- kernel 4: multi-block scan; writes start AND cur (= start copy) ----------
__global__ __launch_bounds__(1024)
void scan_block_atomic(const int* __restrict__ cnt, int* __restrict__ start,
                       int* __restrict__ cur, int* __restrict__ cursor, int n) {
    __shared__ int wsum[16];
    __shared__ int sbase;
    const int tid = threadIdx.x, lane = tid & 63, wid = tid >> 6;
    const int i = blockIdx.x * 1024 + tid;
    const int v = (i < n) ? cnt[i] : 0;
    int x = v;
#pragma unroll
    for (int off = 1; off < 64; off <<= 1) {
        int t = __shfl_up(x, off);
        if (lane >= off) x += t;
    }
    if (lane == 63) wsum[wid] = x;
    __syncthreads();
    if (wid == 0) {
        int w = (lane < 16) ? wsum[lane] : 0;
#pragma unroll
        for (int off = 1; off < 16; off <<= 1) {
            int t = __shfl_up(w, off);
            if (lane >= off) w += t;
        }
        if (lane < 16) wsum[lane] = w;
    }
    __syncthreads();
    const int total = wsum[15];
    if (tid == 0) sbase = atomicAdd(cursor, total);
    __syncthreads();
    const int woff = (wid > 0) ? wsum[wid - 1] : 0;
    if (i < n) {
        const int sv = sbase + woff + x - v;
        start[i] = sv;
        cur[i] = sv;
    }
}

// ---------- kernel 5: scatter CSR records (col, ea as 6xbf16) = 16B/edge ----------
__global__ void scatter_rec(const int* __restrict__ ei, int E, const float* __restrict__ ea,
                            int* __restrict__ cur, uint4* __restrict__ rec) {
    int e = blockIdx.x * blockDim.x + threadIdx.x;
    if (e < E) {
        int row = ei[e];
        int col = ei[E + e];
        const float* ep = ea + (size_t)e * EDGE_DIM;
        unsigned b01 = (unsigned)f2bf(ep[0]) | ((unsigned)f2bf(ep[1]) << 16);
        unsigned b23 = (unsigned)f2bf(ep[2]) | ((unsigned)f2bf(ep[3]) << 16);
        unsigned b45 = (unsigned)f2bf(ep[4]) | ((unsigned)f2bf(ep[5]) << 16);
        int pos = atomicAdd(&cur[row], 1);  // cur pre-initialized to start
        rec[pos] = make_uint4((unsigned)col, b01, b23, b45);
    }
}

// ---------- kernel 6: per-node gather-aggregate + residual + LayerNorm ----------
__global__ __launch_bounds__(256)
void aggregate_ln(const unsigned* __restrict__ h,
                  const int* __restrict__ start, const int* __restrict__ cnt,
                  const uint4* __restrict__ rec,
                  const float* __restrict__ Wc, const float* __restrict__ bc,
                  const unsigned* __restrict__ xtb,
                  const float* __restrict__ gamma, const float* __restrict__ beta,
                  float* __restrict__ out, int nnode) {
    const int lane = threadIdx.x & 63;
    const int wid = threadIdx.x >> 6;

    float2 wc[EDGE_DIM];
#pragma unroll
    for (int k = 0; k < EDGE_DIM; ++k)
        wc[k] = reinterpret_cast<const float2*>(Wc)[k * 64 + lane];
    const float2 bc2 = reinterpret_cast<const float2*>(bc)[lane];
    const float2 g = reinterpret_cast<const float2*>(gamma)[lane];
    const float2 bb = reinterpret_cast<const float2*>(beta)[lane];

    for (int n = blockIdx.x * 4 + wid; n < nnode; n += gridDim.x * 4) {
        const int s = start[n];
        const int c = cnt[n];
        float ax = 0.f, ay = 0.f;
        for (int ibase = 0; ibase < c; ibase += 64) {
            const int m = min(64, c - ibase);
            uint4 rc = make_uint4(0, 0, 0, 0);
            if (lane < m) rc = rec[(size_t)(s + ibase) + lane];
            auto LDH = [&](int j) -> unsigned {
                const int jc = min(j, m - 1);
                const int colj = __builtin_amdgcn_readlane((int)rc.x, jc);
                return h[(unsigned)(colj * 64 + lane)];
            };
            auto COMP = [&](int j, unsigned hv) {
                const unsigned b01 = (unsigned)__builtin_amdgcn_readlane((int)rc.y, j);
                const unsigned b23 = (unsigned)__builtin_amdgcn_readlane((int)rc.z, j);
                const unsigned b45 = (unsigned)__builtin_amdgcn_readlane((int)rc.w, j);
                const float e0 = bf_lo(b01), e1 = bf_hi(b01);
                const float e2 = bf_lo(b23), e3 = bf_hi(b23);
                const float e4 = bf_lo(b45), e5 = bf_hi(b45);
                float vx = bc2.x + bf_lo(hv);
                float vy = bc2.y + bf_hi(hv);
                vx = fmaf(e0, wc[0].x, vx); vy = fmaf(e0, wc[0].y, vy);
                vx = fmaf(e1, wc[1].x, vx); vy = fmaf(e1, wc[1].y, vy);
                vx = fmaf(e2, wc[2].x, vx); vy = fmaf(e2, wc[2].y, vy);
                vx = fmaf(e3, wc[3].x, vx); vy = fmaf(e3, wc[3].y, vy);
                vx = fmaf(e4, wc[4].x, vx); vy = fmaf(e4, wc[4].y, vy);
                vx = fmaf(e5, wc[5].x, vx); vy = fmaf(e5, wc[5].y, vy);
                ax += fmaxf(vx, 0.f);
                ay += fmaxf(vy, 0.f);
            };
            unsigned h0 = LDH(0), h1 = LDH(1), h2 = LDH(2), h3 = LDH(3),
                     h4 = LDH(4), h5 = LDH(5), h6 = LDH(6), h7 = LDH(7);
            int i = 0;
            for (; i + 8 <= m; i += 8) {
                COMP(i + 0, h0); h0 = LDH(i + 8);
                COMP(i + 1, h1); h1 = LDH(i + 9);
                COMP(i + 2, h2); h2 = LDH(i + 10);
                COMP(i + 3, h3); h3 = LDH(i + 11);
                COMP(i + 4, h4); h4 = LDH(i + 12);
                COMP(i + 5, h5); h5 = LDH(i + 13);
                COMP(i + 6, h6); h6 = LDH(i + 14);
                COMP(i + 7, h7); h7 = LDH(i + 15);
            }
            if (i + 0 < m) COMP(i + 0, h0);
            if (i + 1 < m) COMP(i + 1, h1);
            if (i + 2 < m) COMP(i + 2, h2);
            if (i + 3 < m) COMP(i + 3, h3);
            if (i + 4 < m) COMP(i + 4, h4);
            if (i + 5 < m) COMP(i + 5, h5);
            if (i + 6 < m) COMP(i + 6, h6);
        }
        const float inv = 1.0f / fmaxf((float)c, 1.0f);
        const unsigned xu = xtb[(unsigned)(n * 64 + lane)];
        float o0 = fmaf(ax, inv, bf_lo(xu));
        float o1 = fmaf(ay, inv, bf_hi(xu));
        float s1 = o0 + o1, s2 = o0 * o0 + o1 * o1;
#pragma unroll
        for (int off = 32; off; off >>= 1) {
            s1 += __shfl_xor(s1, off);
            s2 += __shfl_xor(s2, off);
        }
        const float mean = s1 * (1.0f / D);
        const float var = s2 * (1.0f / D) - mean * mean;
        const float rstd = rsqrtf(var + LN_EPS);
        float2 r;
        r.x = (o0 - mean) * rstd * g.x + bb.x;
        r.y = (o1 - mean) * rstd * g.y + bb.y;
        reinterpret_cast<float2*>(out)[(size_t)n * 64 + lane] = r;
    }
}

extern "C" void kernel_launch(void* const* d_in, const int* in_sizes, int n_in,
                              void* d_out, int out_size, void* d_ws, size_t ws_size,
                              hipStream_t stream) {
    const float* x     = (const float*)d_in[0];
    const float* eattr = (const float*)d_in[1];
    const float* Wn    = (const float*)d_in[2];
    const float* bn    = (const float*)d_in[3];
    const float* We    = (const float*)d_in[4];
    const float* be    = (const float*)d_in[5];
    const float* Wm    = (const float*)d_in[6];
    const float* bm    = (const float*)d_in[7];
    const float* gamma = (const float*)d_in[8];
    const float* beta  = (const float*)d_in[9];
    const int*   ei    = (const int*)d_in[10];

    const int N = in_sizes[0] / D;
    const int E = in_sizes[10] / 2;

    char* ws = (char*)d_ws;
    unsigned short* xtb = (unsigned short*)ws; ws += (size_t)N * D * 2;
    unsigned short* hb  = (unsigned short*)ws; ws += (size_t)N * D * 2;
    int* ints = (int*)ws;                      ws += (size_t)(N + 4) * 4;  // cnt, cursor
    int* cnt = ints;
    int* cursor = ints + N;
    int* cur    = (int*)ws;                    ws += (size_t)N * 4;
    int* startv = (int*)ws;                    ws += (size_t)N * 4;
    uint4* rec  = (uint4*)ws;                  ws += (size_t)E * 16;
    float* Wnm  = (float*)ws;                  ws += (size_t)D * D * 4;
    float* bnm  = (float*)ws;                  ws += (size_t)D * 4;
    float* Wc   = (float*)ws;                  ws += (size_t)EDGE_DIM * D * 4;
    float* bcv  = (float*)ws;                  ws += (size_t)D * 4;
    unsigned short* Wb = (unsigned short*)ws;  ws += (size_t)2 * 8 * 4 * 64 * 8 * 2;

    hipMemsetAsync(ints, 0, (size_t)(N + 4) * 4, stream);

    setup_all<<<136 + HIST_BLOCKS, 128, 0, stream>>>(Wn, bn, We, be, Wm, bm, ei, E,
                                                     Wnm, bnm, Wc, bcv, cnt);
    pack_wb<<<16, 256, 0, stream>>>(Wn, Wnm, Wb);
    scan_block_atomic<<<(N + 1023) / 1024, 1024, 0, stream>>>(cnt, startv, cur, cursor, N);
    scatter_rec<<<(E + 255) / 256, 256, 0, stream>>>(ei, E, eattr, cur, rec);
    gemm_mfma<<<(((N + 15) / 16) + 3) / 4, 256, 0, stream>>>(x, Wb, bn, bnm, xtb, hb, N);
    aggregate_ln<<<(N + 3) / 4, 256, 0, stream>>>((const unsigned*)hb, startv, cnt, rec,
                                                  Wc, bcv, (const unsigned*)xtb,
                                                  gamma, beta, (float*)d_out, N);
}

// Round 9
// 178.822 us; speedup vs baseline: 1.5115x; 1.0219x over previous
//
#include <hip/hip_runtime.h>
#include <hip/hip_bf16.h>

#define D 128
#define EDGE_DIM 6
#define LN_EPS 1e-5f
#define HIST_BLOCKS 2048

typedef __attribute__((ext_vector_type(8))) short short8;
typedef __attribute__((ext_vector_type(4))) float f32x4;
typedef __attribute__((ext_vector_type(2))) float f32x2;

static __device__ __forceinline__ float bf_lo(unsigned u) { return __uint_as_float(u << 16); }
static __device__ __forceinline__ float bf_hi(unsigned u) { return __uint_as_float(u & 0xffff0000u); }
static __device__ __forceinline__ unsigned short f2bf(float f) {
    __hip_bfloat16 h = __float2bfloat16(f);
    return *reinterpret_cast<unsigned short*>(&h);
}

// ---------- kernel 1: fused setup ----------
// blocks 0..127: Wnm = Wn@Wm1 ; 128: bnm = bn@Wm1 ; 129..134: Wc = We@Wm2 ;
// 135: bc = be@Wm2 + bm ; >=136: histogram of edge rows.
__global__ __launch_bounds__(128)
void setup_all(const float* __restrict__ Wn, const float* __restrict__ bn,
               const float* __restrict__ We, const float* __restrict__ be,
               const float* __restrict__ Wm, const float* __restrict__ bm,
               const int* __restrict__ ei, int E,
               float* __restrict__ Wnm, float* __restrict__ bnm,
               float* __restrict__ Wc, float* __restrict__ bc,
               int* __restrict__ cnt) {
    const int b = blockIdx.x;
    const int d = threadIdx.x;
    if (b < 128) {
        float acc = 0.f;
#pragma unroll 8
        for (int j = 0; j < D; ++j)
            acc = fmaf(Wn[b * D + j], Wm[j * D + d], acc);
        Wnm[b * D + d] = acc;
    } else if (b == 128) {
        float acc = 0.f;
#pragma unroll 8
        for (int j = 0; j < D; ++j)
            acc = fmaf(bn[j], Wm[j * D + d], acc);
        bnm[d] = acc;
    } else if (b < 135) {
        const int k = b - 129;
        float acc = 0.f;
#pragma unroll 8
        for (int j = 0; j < D; ++j)
            acc = fmaf(We[k * D + j], Wm[(D + j) * D + d], acc);
        Wc[k * D + d] = acc;
    } else if (b == 135) {
        float acc = bm[d];
#pragma unroll 8
        for (int j = 0; j < D; ++j)
            acc = fmaf(be[j], Wm[(D + j) * D + d], acc);
        bc[d] = acc;
    } else {
        for (int i = (b - 136) * 128 + d; i < E; i += HIST_BLOCKS * 128)
            atomicAdd(&cnt[ei[i]], 1);
    }
}

// ---------- kernel 2: scan (blocks < nscan) + pack Wb (blocks >= nscan) ----------
__global__ __launch_bounds__(1024)
void scan_pack(const int* __restrict__ cnt, int* __restrict__ start,
               int* __restrict__ cur, int* __restrict__ cursor, int n, int nscan,
               const float* __restrict__ Wn, const float* __restrict__ Wnm,
               unsigned short* __restrict__ Wb) {
    const int tid = threadIdx.x;
    if ((int)blockIdx.x >= nscan) {
        const int idx = ((int)blockIdx.x - nscan) * 1024 + tid;  // 4096 fragments
        if (idx < 4096) {
            const int lane = idx & 63;
            const int s = (idx >> 6) & 3;
            const int ct = (idx >> 8) & 7;
            const int mat = idx >> 11;
            const float* W = mat ? Wnm : Wn;
            const int col = ct * 16 + (lane & 15);
            const int k0 = (lane >> 4) * 8 + 32 * s;
            short8 v;
#pragma unroll
            for (int j = 0; j < 8; ++j)
                v[j] = (short)f2bf(W[(size_t)(k0 + j) * D + col]);
            *reinterpret_cast<short8*>(Wb + (size_t)idx * 8) = v;
        }
        return;
    }
    __shared__ int wsum[16];
    __shared__ int sbase;
    const int lane = tid & 63, wid = tid >> 6;
    const int i = blockIdx.x * 1024 + tid;
    const int v = (i < n) ? cnt[i] : 0;
    int x = v;
#pragma unroll
    for (int off = 1; off < 64; off <<= 1) {
        int t = __shfl_up(x, off);
        if (lane >= off) x += t;
    }
    if (lane == 63) wsum[wid] = x;
    __syncthreads();
    if (wid == 0) {
        int w = (lane < 16) ? wsum[lane] : 0;
#pragma unroll
        for (int off = 1; off < 16; off <<= 1) {
            int t = __shfl_up(w, off);
            if (lane >= off) w += t;
        }
        if (lane < 16) wsum[lane] = w;
    }
    __syncthreads();
    const int total = wsum[15];
    if (tid == 0) sbase = atomicAdd(cursor, total);
    __syncthreads();
    const int woff = (wid > 0) ? wsum[wid - 1] : 0;
    if (i < n) {
        const int sv = sbase + woff + x - v;
        start[i] = sv;
        cur[i] = sv;
    }
}

// ---------- kernel 3: scatter CSR records (col, ea as 6xbf16); ea staged via LDS ----------
__global__ __launch_bounds__(256)
void scatter_rec(const int* __restrict__ ei, int E, const float* __restrict__ ea,
                 int* __restrict__ cur, uint4* __restrict__ rec) {
    __shared__ float sEA[256 * EDGE_DIM];
    const int tid = threadIdx.x;
    const int base = blockIdx.x * 256;
    const size_t gbase = (size_t)base * EDGE_DIM;
    const size_t gtot = (size_t)E * EDGE_DIM;
#pragma unroll
    for (int k = 0; k < EDGE_DIM; ++k) {
        const int idx = k * 256 + tid;
        if (gbase + idx < gtot) sEA[idx] = ea[gbase + idx];
    }
    __syncthreads();
    const int e = base + tid;
    if (e < E) {
        const int row = ei[e];
        const int col = ei[E + e];
        const float* ep = &sEA[tid * EDGE_DIM];
        unsigned b01 = (unsigned)f2bf(ep[0]) | ((unsigned)f2bf(ep[1]) << 16);
        unsigned b23 = (unsigned)f2bf(ep[2]) | ((unsigned)f2bf(ep[3]) << 16);
        unsigned b45 = (unsigned)f2bf(ep[4]) | ((unsigned)f2bf(ep[5]) << 16);
        int pos = atomicAdd(&cur[row], 1);  // cur pre-initialized to start
        rec[pos] = make_uint4((unsigned)col, b01, b23, b45);
    }
}

// ---------- kernel 4: dual MFMA GEMM, one wave per 16-row tile ----------
__global__ __launch_bounds__(64)
void gemm_mfma(const float* __restrict__ x, const unsigned short* __restrict__ Wb,
               const float* __restrict__ bn, const float* __restrict__ bnm,
               unsigned short* __restrict__ xtb, unsigned short* __restrict__ hb,
               int nrows) {
    const int lane = threadIdx.x;
    const int row16 = lane & 15;
    const int kgrp = lane >> 4;  // 0..3
    const int t = blockIdx.x;

    float biasA[8], biasB[8];
#pragma unroll
    for (int ct = 0; ct < 8; ++ct) {
        biasA[ct] = bn[ct * 16 + row16];
        biasB[ct] = bnm[ct * 16 + row16];
    }

    const int ra = t * 16 + row16;
    const bool rv = ra < nrows;
    short8 a[4];
#pragma unroll
    for (int s = 0; s < 4; ++s) {
        const float* xp = x + (size_t)ra * D + kgrp * 8 + 32 * s;
        float4 u0 = rv ? *reinterpret_cast<const float4*>(xp)
                       : make_float4(0.f, 0.f, 0.f, 0.f);
        float4 u1 = rv ? *reinterpret_cast<const float4*>(xp + 4)
                       : make_float4(0.f, 0.f, 0.f, 0.f);
        a[s][0] = (short)f2bf(u0.x); a[s][1] = (short)f2bf(u0.y);
        a[s][2] = (short)f2bf(u0.z); a[s][3] = (short)f2bf(u0.w);
        a[s][4] = (short)f2bf(u1.x); a[s][5] = (short)f2bf(u1.y);
        a[s][6] = (short)f2bf(u1.z); a[s][7] = (short)f2bf(u1.w);
    }
    const int rw0 = t * 16 + kgrp * 4;
#pragma unroll
    for (int mat = 0; mat < 2; ++mat) {
        unsigned short* out = mat ? hb : xtb;
#pragma unroll
        for (int ct = 0; ct < 8; ++ct) {
            f32x4 acc = {0.f, 0.f, 0.f, 0.f};
#pragma unroll
            for (int s = 0; s < 4; ++s) {
                short8 bfr = *reinterpret_cast<const short8*>(
                    Wb + (size_t)((((mat * 8 + ct) * 4 + s) * 64 + lane)) * 8);
                acc = __builtin_amdgcn_mfma_f32_16x16x32_bf16(a[s], bfr, acc, 0, 0, 0);
            }
            const float bsc = mat ? biasB[ct] : biasA[ct];
            const int dcol = ct * 16 + row16;
#pragma unroll
            for (int j = 0; j < 4; ++j) {
                const int r = rw0 + j;
                if (r < nrows) out[(size_t)r * D + dcol] = f2bf(acc[j] + bsc);
            }
        }
    }
}

// ---------- kernel 5: per-node gather-aggregate + residual + LayerNorm ----------
// One wave per node; lane holds dims (2l, 2l+1). Per edge: 3 readlane -> SGPR
// (SALU bf16 unpack) + 6 v_pk_fma_f32 with SGPR-broadcast src0 + 2x v_max + add.
__global__ __launch_bounds__(256)
void aggregate_ln(const unsigned* __restrict__ h,
                  const int* __restrict__ start, const int* __restrict__ cnt,
                  const uint4* __restrict__ rec,
                  const float* __restrict__ Wc, const float* __restrict__ bc,
                  const unsigned* __restrict__ xtb,
                  const float* __restrict__ gamma, const float* __restrict__ beta,
                  float* __restrict__ out, int nnode) {
    const int lane = threadIdx.x & 63;
    const int wid = threadIdx.x >> 6;

    f32x2 wc[EDGE_DIM];
#pragma unroll
    for (int k = 0; k < EDGE_DIM; ++k)
        wc[k] = reinterpret_cast<const f32x2*>(Wc)[k * 64 + lane];
    const f32x2 bc2 = reinterpret_cast<const f32x2*>(bc)[lane];
    const f32x2 g = reinterpret_cast<const f32x2*>(gamma)[lane];
    const f32x2 bb = reinterpret_cast<const f32x2*>(beta)[lane];

    for (int n = blockIdx.x * 4 + wid; n < nnode; n += gridDim.x * 4) {
        const int s = start[n];
        const int c = cnt[n];
        f32x2 axy = {0.f, 0.f};
        for (int ibase = 0; ibase < c; ibase += 64) {
            const int m = min(64, c - ibase);
            uint4 rc = make_uint4(0, 0, 0, 0);
            if (lane < m) rc = rec[(size_t)(s + ibase) + lane];
            auto LDH = [&](int j) -> unsigned {
                const int jc = min(j, m - 1);
                const int colj = __builtin_amdgcn_readlane((int)rc.x, jc);
                return h[(unsigned)(colj * 64 + lane)];
            };
            auto COMP = [&](int j, unsigned hv) {
                const unsigned b01 = (unsigned)__builtin_amdgcn_readlane((int)rc.y, j);
                const unsigned b23 = (unsigned)__builtin_amdgcn_readlane((int)rc.z, j);
                const unsigned b45 = (unsigned)__builtin_amdgcn_readlane((int)rc.w, j);
                f32x2 e01, e23, e45, hx, msg;
                e01[0] = bf_lo(b01); e01[1] = bf_hi(b01);   // uniform -> SALU
                e23[0] = bf_lo(b23); e23[1] = bf_hi(b23);
                e45[0] = bf_lo(b45); e45[1] = bf_hi(b45);
                hx[0] = bf_lo(hv); hx[1] = bf_hi(hv);
                asm("v_pk_add_f32 %0, %1, %2" : "=v"(msg) : "v"(bc2), "v"(hx));
                asm("v_pk_fma_f32 %0, %1, %2, %0 op_sel:[0,0,0] op_sel_hi:[0,1,1]"
                    : "+v"(msg) : "s"(e01), "v"(wc[0]));
                asm("v_pk_fma_f32 %0, %1, %2, %0 op_sel:[1,0,0] op_sel_hi:[1,1,1]"
                    : "+v"(msg) : "s"(e01), "v"(wc[1]));
                asm("v_pk_fma_f32 %0, %1, %2, %0 op_sel:[0,0,0] op_sel_hi:[0,1,1]"
                    : "+v"(msg) : "s"(e23), "v"(wc[2]));
                asm("v_pk_fma_f32 %0, %1, %2, %0 op_sel:[1,0,0] op_sel_hi:[1,1,1]"
                    : "+v"(msg) : "s"(e23), "v"(wc[3]));
                asm("v_pk_fma_f32 %0, %1, %2, %0 op_sel:[0,0,0] op_sel_hi:[0,1,1]"
                    : "+v"(msg) : "s"(e45), "v"(wc[4]));
                asm("v_pk_fma_f32 %0, %1, %2, %0 op_sel:[1,0,0] op_sel_hi:[1,1,1]"
                    : "+v"(msg) : "s"(e45), "v"(wc[5]));
                // no v_pk_max_f32 on gfx950 -> scalar relu + accumulate
                axy[0] += fmaxf(msg[0], 0.f);
                axy[1] += fmaxf(msg[1], 0.f);
            };
            unsigned h0 = LDH(0), h1 = LDH(1), h2 = LDH(2), h3 = LDH(3),
                     h4 = LDH(4), h5 = LDH(5), h6 = LDH(6), h7 = LDH(7);
            int i = 0;
            for (; i + 8 <= m; i += 8) {
                COMP(i + 0, h0); h0 = LDH(i + 8);
                COMP(i + 1, h1); h1 = LDH(i + 9);
                COMP(i + 2, h2); h2 = LDH(i + 10);
                COMP(i + 3, h3); h3 = LDH(i + 11);
                COMP(i + 4, h4); h4 = LDH(i + 12);
                COMP(i + 5, h5); h5 = LDH(i + 13);
                COMP(i + 6, h6); h6 = LDH(i + 14);
                COMP(i + 7, h7); h7 = LDH(i + 15);
            }
            if (i + 0 < m) COMP(i + 0, h0);
            if (i + 1 < m) COMP(i + 1, h1);
            if (i + 2 < m) COMP(i + 2, h2);
            if (i + 3 < m) COMP(i + 3, h3);
            if (i + 4 < m) COMP(i + 4, h4);
            if (i + 5 < m) COMP(i + 5, h5);
            if (i + 6 < m) COMP(i + 6, h6);
        }
        const float inv = 1.0f / fmaxf((float)c, 1.0f);
        const unsigned xu = xtb[(unsigned)(n * 64 + lane)];
        float o0 = fmaf(axy[0], inv, bf_lo(xu));
        float o1 = fmaf(axy[1], inv, bf_hi(xu));
        float s1 = o0 + o1, s2 = o0 * o0 + o1 * o1;
#pragma unroll
        for (int off = 32; off; off >>= 1) {
            s1 += __shfl_xor(s1, off);
            s2 += __shfl_xor(s2, off);
        }
        const float mean = s1 * (1.0f / D);
        const float var = s2 * (1.0f / D) - mean * mean;
        const float rstd = rsqrtf(var + LN_EPS);
        float2 r;
        r.x = (o0 - mean) * rstd * g[0] + bb[0];
        r.y = (o1 - mean) * rstd * g[1] + bb[1];
        reinterpret_cast<float2*>(out)[(size_t)n * 64 + lane] = r;
    }
}

extern "C" void kernel_launch(void* const* d_in, const int* in_sizes, int n_in,
                              void* d_out, int out_size, void* d_ws, size_t ws_size,
                              hipStream_t stream) {
    const float* x     = (const float*)d_in[0];
    const float* eattr = (const float*)d_in[1];
    const float* Wn    = (const float*)d_in[2];
    const float* bn    = (const float*)d_in[3];
    const float* We    = (const float*)d_in[4];
    const float* be    = (const float*)d_in[5];
    const float* Wm    = (const float*)d_in[6];
    const float* bm    = (const float*)d_in[7];
    const float* gamma = (const float*)d_in[8];
    const float* beta  = (const float*)d_in[9];
    const int*   ei    = (const int*)d_in[10];

    const int N = in_sizes[0] / D;
    const int E = in_sizes[10] / 2;

    char* ws = (char*)d_ws;
    unsigned short* xtb = (unsigned short*)ws; ws += (size_t)N * D * 2;
    unsigned short* hb  = (unsigned short*)ws; ws += (size_t)N * D * 2;
    int* ints = (int*)ws;                      ws += (size_t)(N + 4) * 4;  // cnt, cursor
    int* cnt = ints;
    int* cursor = ints + N;
    int* cur    = (int*)ws;                    ws += (size_t)N * 4;
    int* startv = (int*)ws;                    ws += (size_t)N * 4;
    uint4* rec  = (uint4*)ws;                  ws += (size_t)E * 16;
    float* Wnm  = (float*)ws;                  ws += (size_t)D * D * 4;
    float* bnm  = (float*)ws;                  ws += (size_t)D * 4;
    float* Wc   = (float*)ws;                  ws += (size_t)EDGE_DIM * D * 4;
    float* bcv  = (float*)ws;                  ws += (size_t)D * 4;
    unsigned short* Wb = (unsigned short*)ws;  ws += (size_t)4096 * 8 * 2;

    const int nscan = (N + 1023) / 1024;
    const int ntile = (N + 15) / 16;

    hipMemsetAsync(ints, 0, (size_t)(N + 4) * 4, stream);

    setup_all<<<136 + HIST_BLOCKS, 128, 0, stream>>>(Wn, bn, We, be, Wm, bm, ei, E,
                                                     Wnm, bnm, Wc, bcv, cnt);
    scan_pack<<<nscan + 4, 1024, 0, stream>>>(cnt, startv, cur, cursor, N, nscan,
                                              Wn, Wnm, Wb);
    scatter_rec<<<(E + 255) / 256, 256, 0, stream>>>(ei, E, eattr, cur, rec);
    gemm_mfma<<<ntile, 64, 0, stream>>>(x, Wb, bn, bnm, xtb, hb, N);
    aggregate_ln<<<(N + 3) / 4, 256, 0, stream>>>((const unsigned*)hb, startv, cnt, rec,
                                                  Wc, bcv, (const unsigned*)xtb,
                                                  gamma, beta, (float*)d_out, N);
}

// Round 10
// 173.218 us; speedup vs baseline: 1.5604x; 1.0324x over previous
//
#include <hip/hip_runtime.h>
#include <hip/hip_bf16.h>

#define D 128
#define EDGE_DIM 6
#define LN_EPS 1e-5f
#define HIST_BLOCKS 2048

typedef __attribute__((ext_vector_type(8))) short short8;
typedef __attribute__((ext_vector_type(4))) float f32x4;
typedef __attribute__((ext_vector_type(2))) float f32x2;

static __device__ __forceinline__ float bf_lo(unsigned u) { return __uint_as_float(u << 16); }
static __device__ __forceinline__ float bf_hi(unsigned u) { return __uint_as_float(u & 0xffff0000u); }
static __device__ __forceinline__ unsigned short f2bf(float f) {
    __hip_bfloat16 h = __float2bfloat16(f);
    return *reinterpret_cast<unsigned short*>(&h);
}

// ---------- kernel 1: fused setup ----------
// blocks 0..127: Wnm = Wn@Wm1 ; 128: bnm = bn@Wm1 ; 129..134: Wc = We@Wm2 ;
// 135: bc = be@Wm2 + bm ; >=136: histogram of edge rows.
__global__ __launch_bounds__(128)
void setup_all(const float* __restrict__ Wn, const float* __restrict__ bn,
               const float* __restrict__ We, const float* __restrict__ be,
               const float* __restrict__ Wm, const float* __restrict__ bm,
               const int* __restrict__ ei, int E,
               float* __restrict__ Wnm, float* __restrict__ bnm,
               float* __restrict__ Wc, float* __restrict__ bc,
               int* __restrict__ cnt) {
    const int b = blockIdx.x;
    const int d = threadIdx.x;
    if (b < 128) {
        float acc = 0.f;
#pragma unroll 8
        for (int j = 0; j < D; ++j)
            acc = fmaf(Wn[b * D + j], Wm[j * D + d], acc);
        Wnm[b * D + d] = acc;
    } else if (b == 128) {
        float acc = 0.f;
#pragma unroll 8
        for (int j = 0; j < D; ++j)
            acc = fmaf(bn[j], Wm[j * D + d], acc);
        bnm[d] = acc;
    } else if (b < 135) {
        const int k = b - 129;
        float acc = 0.f;
#pragma unroll 8
        for (int j = 0; j < D; ++j)
            acc = fmaf(We[k * D + j], Wm[(D + j) * D + d], acc);
        Wc[k * D + d] = acc;
    } else if (b == 135) {
        float acc = bm[d];
#pragma unroll 8
        for (int j = 0; j < D; ++j)
            acc = fmaf(be[j], Wm[(D + j) * D + d], acc);
        bc[d] = acc;
    } else {
        for (int i = (b - 136) * 128 + d; i < E; i += HIST_BLOCKS * 128)
            atomicAdd(&cnt[ei[i]], 1);
    }
}

// ---------- kernel 2: scan (blocks < nscan) + pack Wb (blocks >= nscan) ----------
__global__ __launch_bounds__(1024)
void scan_pack(const int* __restrict__ cnt, int* __restrict__ start,
               int* __restrict__ cur, int* __restrict__ cursor, int n, int nscan,
               const float* __restrict__ Wn, const float* __restrict__ Wnm,
               unsigned short* __restrict__ Wb) {
    const int tid = threadIdx.x;
    if ((int)blockIdx.x >= nscan) {
        const int idx = ((int)blockIdx.x - nscan) * 1024 + tid;  // 4096 fragments
        if (idx < 4096) {
            const int lane = idx & 63;
            const int s = (idx >> 6) & 3;
            const int ct = (idx >> 8) & 7;
            const int mat = idx >> 11;
            const float* W = mat ? Wnm : Wn;
            const int col = ct * 16 + (lane & 15);
            const int k0 = (lane >> 4) * 8 + 32 * s;
            short8 v;
#pragma unroll
            for (int j = 0; j < 8; ++j)
                v[j] = (short)f2bf(W[(size_t)(k0 + j) * D + col]);
            *reinterpret_cast<short8*>(Wb + (size_t)idx * 8) = v;
        }
        return;
    }
    __shared__ int wsum[16];
    __shared__ int sbase;
    const int lane = tid & 63, wid = tid >> 6;
    const int i = blockIdx.x * 1024 + tid;
    const int v = (i < n) ? cnt[i] : 0;
    int x = v;
#pragma unroll
    for (int off = 1; off < 64; off <<= 1) {
        int t = __shfl_up(x, off);
        if (lane >= off) x += t;
    }
    if (lane == 63) wsum[wid] = x;
    __syncthreads();
    if (wid == 0) {
        int w = (lane < 16) ? wsum[lane] : 0;
#pragma unroll
        for (int off = 1; off < 16; off <<= 1) {
            int t = __shfl_up(w, off);
            if (lane >= off) w += t;
        }
        if (lane < 16) wsum[lane] = w;
    }
    __syncthreads();
    const int total = wsum[15];
    if (tid == 0) sbase = atomicAdd(cursor, total);
    __syncthreads();
    const int woff = (wid > 0) ? wsum[wid - 1] : 0;
    if (i < n) {
        const int sv = sbase + woff + x - v;
        start[i] = sv;
        cur[i] = sv;
    }
}

// ---------- kernel 3: scatter CSR records, 8 edges/thread, batched atomics ----------
// Block = 2048 edges. Phase 1: stage+pack ea into LDS (coalesced float2 reads).
// Phase 2: 8 independent atomicAdd round-trips in flight, then 8 stores.
__global__ __launch_bounds__(256)
void scatter_rec(const int* __restrict__ ei, int E, const float* __restrict__ ea,
                 int* __restrict__ cur, uint4* __restrict__ rec) {
    __shared__ unsigned sR[2048 * 3];  // 24 KB: (b01,b23,b45) per edge
    const int tid = threadIdx.x;
    const int base = blockIdx.x * 2048;
    const int nrec = min(2048, E - base);
    const float2* ea2 = reinterpret_cast<const float2*>(ea);
    for (int i = tid; i < nrec * 3; i += 256) {
        float2 p = ea2[(size_t)base * 3 + i];
        sR[i] = (unsigned)f2bf(p.x) | ((unsigned)f2bf(p.y) << 16);
    }
    __syncthreads();

    int rows[8], cols[8], pos[8];
#pragma unroll
    for (int it = 0; it < 8; ++it) {
        const int e = base + it * 256 + tid;
        const bool val = e < E;
        rows[it] = val ? ei[e] : -1;
        cols[it] = val ? ei[E + e] : 0;
    }
#pragma unroll
    for (int it = 0; it < 8; ++it)
        if (rows[it] >= 0) pos[it] = atomicAdd(&cur[rows[it]], 1);
#pragma unroll
    for (int it = 0; it < 8; ++it)
        if (rows[it] >= 0) {
            const int le = (it * 256 + tid) * 3;
            rec[pos[it]] = make_uint4((unsigned)cols[it], sR[le], sR[le + 1], sR[le + 2]);
        }
}

// ---------- kernel 4: dual MFMA GEMM, one wave per 16-row tile ----------
__global__ __launch_bounds__(64)
void gemm_mfma(const float* __restrict__ x, const unsigned short* __restrict__ Wb,
               const float* __restrict__ bn, const float* __restrict__ bnm,
               unsigned short* __restrict__ xtb, unsigned short* __restrict__ hb,
               int nrows) {
    const int lane = threadIdx.x;
    const int row16 = lane & 15;
    const int kgrp = lane >> 4;  // 0..3
    const int t = blockIdx.x;

    float biasA[8], biasB[8];
#pragma unroll
    for (int ct = 0; ct < 8; ++ct) {
        biasA[ct] = bn[ct * 16 + row16];
        biasB[ct] = bnm[ct * 16 + row16];
    }

    const int ra = t * 16 + row16;
    const bool rv = ra < nrows;
    short8 a[4];
#pragma unroll
    for (int s = 0; s < 4; ++s) {
        const float* xp = x + (size_t)ra * D + kgrp * 8 + 32 * s;
        float4 u0 = rv ? *reinterpret_cast<const float4*>(xp)
                       : make_float4(0.f, 0.f, 0.f, 0.f);
        float4 u1 = rv ? *reinterpret_cast<const float4*>(xp + 4)
                       : make_float4(0.f, 0.f, 0.f, 0.f);
        a[s][0] = (short)f2bf(u0.x); a[s][1] = (short)f2bf(u0.y);
        a[s][2] = (short)f2bf(u0.z); a[s][3] = (short)f2bf(u0.w);
        a[s][4] = (short)f2bf(u1.x); a[s][5] = (short)f2bf(u1.y);
        a[s][6] = (short)f2bf(u1.z); a[s][7] = (short)f2bf(u1.w);
    }
    const int rw0 = t * 16 + kgrp * 4;
#pragma unroll
    for (int mat = 0; mat < 2; ++mat) {
        unsigned short* out = mat ? hb : xtb;
#pragma unroll
        for (int ct = 0; ct < 8; ++ct) {
            f32x4 acc = {0.f, 0.f, 0.f, 0.f};
#pragma unroll
            for (int s = 0; s < 4; ++s) {
                short8 bfr = *reinterpret_cast<const short8*>(
                    Wb + (size_t)((((mat * 8 + ct) * 4 + s) * 64 + lane)) * 8);
                acc = __builtin_amdgcn_mfma_f32_16x16x32_bf16(a[s], bfr, acc, 0, 0, 0);
            }
            const float bsc = mat ? biasB[ct] : biasA[ct];
            const int dcol = ct * 16 + row16;
#pragma unroll
            for (int j = 0; j < 4; ++j) {
                const int r = rw0 + j;
                if (r < nrows) out[(size_t)r * D + dcol] = f2bf(acc[j] + bsc);
            }
        }
    }
}

// ---------- kernel 5: per-node gather-aggregate + residual + LayerNorm ----------
// One wave per node; lane holds dims (2l, 2l+1). Per edge: uniform-base (SALU)
// gather addressing + two independent pk-FMA chains + scalar relu/acc.
__global__ __launch_bounds__(256)
void aggregate_ln(const unsigned* __restrict__ h,
                  const int* __restrict__ start, const int* __restrict__ cnt,
                  const uint4* __restrict__ rec,
                  const float* __restrict__ Wc, const float* __restrict__ bc,
                  const unsigned* __restrict__ xtb,
                  const float* __restrict__ gamma, const float* __restrict__ beta,
                  float* __restrict__ out, int nnode) {
    const int lane = threadIdx.x & 63;
    const int wid = threadIdx.x >> 6;

    f32x2 wc[EDGE_DIM];
#pragma unroll
    for (int k = 0; k < EDGE_DIM; ++k)
        wc[k] = reinterpret_cast<const f32x2*>(Wc)[k * 64 + lane];
    const f32x2 bc2 = reinterpret_cast<const f32x2*>(bc)[lane];
    const f32x2 g = reinterpret_cast<const f32x2*>(gamma)[lane];
    const f32x2 bb = reinterpret_cast<const f32x2*>(beta)[lane];

    for (int n = blockIdx.x * 4 + wid; n < nnode; n += gridDim.x * 4) {
        const int s = start[n];
        const int c = cnt[n];
        const unsigned xu = xtb[(unsigned)(n * 64 + lane)];  // hoisted, overlaps loop
        f32x2 axy = {0.f, 0.f};
        for (int ibase = 0; ibase < c; ibase += 64) {
            const int m = min(64, c - ibase);
            uint4 rc = make_uint4(0, 0, 0, 0);
            if (lane < m) rc = rec[(size_t)(s + ibase) + lane];
            // colj is wave-uniform (readlane) -> base math on SALU, voffset = lane*4.
            auto LDH = [&](int j) -> unsigned {
                const int jc = min(j, m - 1);
                const unsigned colj = (unsigned)__builtin_amdgcn_readlane((int)rc.x, jc);
                const unsigned* hrow = h + ((size_t)colj << 6);
                return hrow[lane];
            };
            auto COMP = [&](int j, unsigned hv) {
                const unsigned b01 = (unsigned)__builtin_amdgcn_readlane((int)rc.y, j);
                const unsigned b23 = (unsigned)__builtin_amdgcn_readlane((int)rc.z, j);
                const unsigned b45 = (unsigned)__builtin_amdgcn_readlane((int)rc.w, j);
                f32x2 e01, e23, e45, hx, mA, mB;
                e01[0] = bf_lo(b01); e01[1] = bf_hi(b01);   // uniform -> SALU
                e23[0] = bf_lo(b23); e23[1] = bf_hi(b23);
                e45[0] = bf_lo(b45); e45[1] = bf_hi(b45);
                hx[0] = bf_lo(hv); hx[1] = bf_hi(hv);
                // chain A: bc+h + e0*wc0 + e2*wc2 + e4*wc4 ; chain B: e1*wc1 + e3*wc3 + e5*wc5
                asm("v_pk_add_f32 %0, %1, %2" : "=v"(mA) : "v"(bc2), "v"(hx));
                asm("v_pk_mul_f32 %0, %1, %2 op_sel:[1,0] op_sel_hi:[1,1]"
                    : "=v"(mB) : "s"(e01), "v"(wc[1]));
                asm("v_pk_fma_f32 %0, %1, %2, %0 op_sel:[0,0,0] op_sel_hi:[0,1,1]"
                    : "+v"(mA) : "s"(e01), "v"(wc[0]));
                asm("v_pk_fma_f32 %0, %1, %2, %0 op_sel:[1,0,0] op_sel_hi:[1,1,1]"
                    : "+v"(mB) : "s"(e23), "v"(wc[3]));
                asm("v_pk_fma_f32 %0, %1, %2, %0 op_sel:[0,0,0] op_sel_hi:[0,1,1]"
                    : "+v"(mA) : "s"(e23), "v"(wc[2]));
                asm("v_pk_fma_f32 %0, %1, %2, %0 op_sel:[1,0,0] op_sel_hi:[1,1,1]"
                    : "+v"(mB) : "s"(e45), "v"(wc[5]));
                asm("v_pk_fma_f32 %0, %1, %2, %0 op_sel:[0,0,0] op_sel_hi:[0,1,1]"
                    : "+v"(mA) : "s"(e45), "v"(wc[4]));
                asm("v_pk_add_f32 %0, %0, %1" : "+v"(mA) : "v"(mB));
                axy[0] += fmaxf(mA[0], 0.f);
                axy[1] += fmaxf(mA[1], 0.f);
            };
            unsigned h0 = LDH(0), h1 = LDH(1), h2 = LDH(2), h3 = LDH(3),
                     h4 = LDH(4), h5 = LDH(5), h6 = LDH(6), h7 = LDH(7);
            int i = 0;
            for (; i + 8 <= m; i += 8) {
                COMP(i + 0, h0); h0 = LDH(i + 8);
                COMP(i + 1, h1); h1 = LDH(i + 9);
                COMP(i + 2, h2); h2 = LDH(i + 10);
                COMP(i + 3, h3); h3 = LDH(i + 11);
                COMP(i + 4, h4); h4 = LDH(i + 12);
                COMP(i + 5, h5); h5 = LDH(i + 13);
                COMP(i + 6, h6); h6 = LDH(i + 14);
                COMP(i + 7, h7); h7 = LDH(i + 15);
            }
            if (i + 0 < m) COMP(i + 0, h0);
            if (i + 1 < m) COMP(i + 1, h1);
            if (i + 2 < m) COMP(i + 2, h2);
            if (i + 3 < m) COMP(i + 3, h3);
            if (i + 4 < m) COMP(i + 4, h4);
            if (i + 5 < m) COMP(i + 5, h5);
            if (i + 6 < m) COMP(i + 6, h6);
        }
        const float inv = 1.0f / fmaxf((float)c, 1.0f);
        float o0 = fmaf(axy[0], inv, bf_lo(xu));
        float o1 = fmaf(axy[1], inv, bf_hi(xu));
        float s1 = o0 + o1, s2 = o0 * o0 + o1 * o1;
#pragma unroll
        for (int off = 32; off; off >>= 1) {
            s1 += __shfl_xor(s1, off);
            s2 += __shfl_xor(s2, off);
        }
        const float mean = s1 * (1.0f / D);
        const float var = s2 * (1.0f / D) - mean * mean;
        const float rstd = rsqrtf(var + LN_EPS);
        float2 r;
        r.x = (o0 - mean) * rstd * g[0] + bb[0];
        r.y = (o1 - mean) * rstd * g[1] + bb[1];
        reinterpret_cast<float2*>(out)[(size_t)n * 64 + lane] = r;
    }
}

extern "C" void kernel_launch(void* const* d_in, const int* in_sizes, int n_in,
                              void* d_out, int out_size, void* d_ws, size_t ws_size,
                              hipStream_t stream) {
    const float* x     = (const float*)d_in[0];
    const float* eattr = (const float*)d_in[1];
    const float* Wn    = (const float*)d_in[2];
    const float* bn    = (const float*)d_in[3];
    const float* We    = (const float*)d_in[4];
    const float* be    = (const float*)d_in[5];
    const float* Wm    = (const float*)d_in[6];
    const float* bm    = (const float*)d_in[7];
    const float* gamma = (const float*)d_in[8];
    const float* beta  = (const float*)d_in[9];
    const int*   ei    = (const int*)d_in[10];

    const int N = in_sizes[0] / D;
    const int E = in_sizes[10] / 2;

    char* ws = (char*)d_ws;
    unsigned short* xtb = (unsigned short*)ws; ws += (size_t)N * D * 2;
    unsigned short* hb  = (unsigned short*)ws; ws += (size_t)N * D * 2;
    int* ints = (int*)ws;                      ws += (size_t)(N + 4) * 4;  // cnt, cursor
    int* cnt = ints;
    int* cursor = ints + N;
    int* cur    = (int*)ws;                    ws += (size_t)N * 4;
    int* startv = (int*)ws;                    ws += (size_t)N * 4;
    uint4* rec  = (uint4*)ws;                  ws += (size_t)E * 16;
    float* Wnm  = (float*)ws;                  ws += (size_t)D * D * 4;
    float* bnm  = (float*)ws;                  ws += (size_t)D * 4;
    float* Wc   = (float*)ws;                  ws += (size_t)EDGE_DIM * D * 4;
    float* bcv  = (float*)ws;                  ws += (size_t)D * 4;
    unsigned short* Wb = (unsigned short*)ws;  ws += (size_t)4096 * 8 * 2;

    const int nscan = (N + 1023) / 1024;
    const int ntile = (N + 15) / 16;

    hipMemsetAsync(ints, 0, (size_t)(N + 4) * 4, stream);

    setup_all<<<136 + HIST_BLOCKS, 128, 0, stream>>>(Wn, bn, We, be, Wm, bm, ei, E,
                                                     Wnm, bnm, Wc, bcv, cnt);
    scan_pack<<<nscan + 4, 1024, 0, stream>>>(cnt, startv, cur, cursor, N, nscan,
                                              Wn, Wnm, Wb);
    scatter_rec<<<(E + 2047) / 2048, 256, 0, stream>>>(ei, E, eattr, cur, rec);
    gemm_mfma<<<ntile, 64, 0, stream>>>(x, Wb, bn, bnm, xtb, hb, N);
    aggregate_ln<<<(N + 3) / 4, 256, 0, stream>>>((const unsigned*)hb, startv, cnt, rec,
                                                  Wc, bcv, (const unsigned*)xtb,
                                                  gamma, beta, (float*)d_out, N);
}